// Round 1
// baseline (11902.682 us; speedup 1.0000x reference)
//
#include <hip/hip_runtime.h>
#include <stdint.h>

// BidirectionalRNNClassifier on MI355X.
//   embed = inp @ U / 16 + b              (MFMA bf16 hi/lo, ~fp32 accurate)
//   512 sequential steps x 2 directions:  carry = erf(e_t + carry) @ W / 32
//   out = [s_fwd_last, s_bwd_last] @ v / 32
// Recurrence: 4 independent groups (dir x batch-half of 32 rows), 64 wgs each.
// Each wg owns a 16-col slice of W in LDS (bf16 hi+lo). Per step: local erf,
// publish bf16 s-slice + release flag, poll 64 flags, acquire fence, MFMA.

#define TS 512
#define NB 64
#define DI 256
#define DD 1024

typedef float f32x4 __attribute__((ext_vector_type(4)));
typedef short bf16x8 __attribute__((ext_vector_type(8)));

__device__ __forceinline__ unsigned short f32_bf16(float x){
  unsigned u = __float_as_uint(x);
  u += 0x7FFFu + ((u >> 16) & 1u);          // round-nearest-even
  return (unsigned short)(u >> 16);
}
__device__ __forceinline__ float bf16_f32(unsigned short h){
  return __uint_as_float(((unsigned)h) << 16);
}

// ---- W prep: split fp32 W into bf16 hi/lo in MFMA-frag-linear layout ----
// slice j (16 cols), kstep ks (32 k), lane l, elem e:
//   value = W[k][n], k = ks*32 + 8*(l>>4) + e, n = j*16 + (l&15)
//   index = j*16384 + ks*512 + l*8 + e
__global__ __launch_bounds__(256) void wprep(const float* __restrict__ W,
                                             unsigned short* __restrict__ whi,
                                             unsigned short* __restrict__ wlo){
  int idx = blockIdx.x * 256 + threadIdx.x;   // = k*1024 + n, 1M total
  int k = idx >> 10, n = idx & 1023;
  float w = W[idx];
  unsigned short h  = f32_bf16(w);
  unsigned short lo = f32_bf16(w - bf16_f32(h));
  int j    = n >> 4;
  int lane = (((k & 31) >> 3) << 4) | (n & 15);
  int ks   = k >> 5;
  int e    = k & 7;
  int o = (((j << 5) | ks) << 9) | (lane << 3) | e;
  whi[o] = h; wlo[o] = lo;
}

// ---- embed GEMM: e[t][b][d] = sum_i inp[b][t][i]*U[i][d]/16 + bias[d] ----
// 64x64 output tile per wg, K=256 staged in two 128-chunks, bf16 hi/lo 3-MFMA.
template<int EF32>
__global__ __launch_bounds__(256, 2) void embed_k(const float* __restrict__ inp,
                                                  const float* __restrict__ U,
                                                  const float* __restrict__ bias,
                                                  void* __restrict__ e_out){
  __shared__ __attribute__((aligned(16))) unsigned short Ah[8192], Al[8192], Bh[8192], Bl[8192];
  const int tid = threadIdx.x;
  const int w = tid >> 6, l = tid & 63;
  const int bx = blockIdx.x;
  const int tc = bx & 15, tr = bx >> 4;
  const int R0 = tr * 64, C0 = tc * 64;

  f32x4 acc[4];
  #pragma unroll
  for (int nt = 0; nt < 4; ++nt) acc[nt] = (f32x4){0.f, 0.f, 0.f, 0.f};

  for (int kc = 0; kc < 2; ++kc){
    if (kc) __syncthreads();
    // stage A (rows R0..R0+63, 128 k) as hi/lo bf16, XOR-swizzled
    unsigned int* AhU = (unsigned int*)Ah;
    unsigned int* AlU = (unsigned int*)Al;
    for (int it = 0; it < 8; ++it){
      int fi = it * 256 + tid;
      int r = fi >> 5, k4 = fi & 31;
      float4 a = *(const float4*)&inp[((size_t)(R0 + r)) * DI + kc * 128 + k4 * 4];
      unsigned short hx = f32_bf16(a.x), hy = f32_bf16(a.y), hz = f32_bf16(a.z), hw = f32_bf16(a.w);
      unsigned short lx = f32_bf16(a.x - bf16_f32(hx)), ly = f32_bf16(a.y - bf16_f32(hy));
      unsigned short lz = f32_bf16(a.z - bf16_f32(hz)), lw = f32_bf16(a.w - bf16_f32(hw));
      int o = (r * 64 + k4 * 2) ^ ((r & 7) << 2);   // u32 index, byte-XOR bits 4..6
      AhU[o]     = (unsigned)hx | ((unsigned)hy << 16);
      AhU[o + 1] = (unsigned)hz | ((unsigned)hw << 16);
      AlU[o]     = (unsigned)lx | ((unsigned)ly << 16);
      AlU[o + 1] = (unsigned)lz | ((unsigned)lw << 16);
    }
    // stage B = U[k][C0+c] transposed to [c][k]
    for (int it = 0; it < 8; ++it){
      int fi = it * 256 + tid;
      int kk = fi >> 4, c4 = fi & 15;
      float4 u4 = *(const float4*)&U[((size_t)(kc * 128 + kk)) * DD + C0 + c4 * 4];
      float vals[4] = {u4.x, u4.y, u4.z, u4.w};
      #pragma unroll
      for (int q = 0; q < 4; ++q){
        int c = c4 * 4 + q;
        unsigned short h  = f32_bf16(vals[q]);
        unsigned short lo = f32_bf16(vals[q] - bf16_f32(h));
        int o = (c * 128 + kk) ^ ((c & 7) << 3);    // ushort index
        Bh[o] = h; Bl[o] = lo;
      }
    }
    __syncthreads();
    const int arow = (w << 4) | (l & 15);
    const int koff = (l >> 4) << 3;
    #pragma unroll
    for (int ks = 0; ks < 4; ++ks){
      int ao = (arow * 128 + ks * 32 + koff) ^ ((arow & 7) << 3);
      bf16x8 ah = *(const bf16x8*)&Ah[ao];
      bf16x8 al = *(const bf16x8*)&Al[ao];
      #pragma unroll
      for (int nt = 0; nt < 4; ++nt){
        int brow = (nt << 4) | (l & 15);
        int bo = (brow * 128 + ks * 32 + koff) ^ ((brow & 7) << 3);
        bf16x8 bh = *(const bf16x8*)&Bh[bo];
        bf16x8 bl = *(const bf16x8*)&Bl[bo];
        acc[nt] = __builtin_amdgcn_mfma_f32_16x16x32_bf16(ah, bh, acc[nt], 0, 0, 0);
        acc[nt] = __builtin_amdgcn_mfma_f32_16x16x32_bf16(ah, bl, acc[nt], 0, 0, 0);
        acc[nt] = __builtin_amdgcn_mfma_f32_16x16x32_bf16(al, bh, acc[nt], 0, 0, 0);
      }
    }
  }
  #pragma unroll
  for (int nt = 0; nt < 4; ++nt){
    int d = C0 + (nt << 4) + (l & 15);
    float bv = bias[d];
    #pragma unroll
    for (int i = 0; i < 4; ++i){
      int R = R0 + (w << 4) + ((l >> 4) << 2) + i;
      int b = R >> 9, t = R & 511;                   // inp row = b*512 + t
      float val = acc[nt][i] * 0.0625f + bv;         // / sqrt(256)
      size_t eo = (((size_t)(t * NB + b)) << 10) | (unsigned)d;
      if (EF32) ((float*)e_out)[eo] = val;
      else      ((unsigned short*)e_out)[eo] = f32_bf16(val);
    }
  }
}

template<int EF32>
__device__ __forceinline__ float load_e(const void* e, int te, int b, int d){
  size_t o = (((size_t)(te * NB + b)) << 10) | (unsigned)d;
  if (EF32) return ((const float*)e)[o];
  return bf16_f32(((const unsigned short*)e)[o]);
}

// ---- recurrence: 256 wgs x 128 threads, flag-synced within 4 groups ----
template<int EF32>
__global__ __launch_bounds__(128, 1) void recur(const void* __restrict__ e_in,
                                                const unsigned short* __restrict__ whi,
                                                const unsigned short* __restrict__ wlo,
                                                unsigned short* __restrict__ sbuf,
                                                float* __restrict__ sfin,
                                                unsigned int* __restrict__ flags){
  __shared__ __attribute__((aligned(16))) unsigned short Wh[16384], Wl[16384]; // 64 KB
  const int tid = threadIdx.x;
  const int w = tid >> 6, l = tid & 63;
  const int bid = blockIdx.x;
  const int g = bid >> 6;           // group = dir*2 + batch-chunk
  const int j = bid & 63;           // N-slice (16 cols)
  const int dir = g >> 1, bch = g & 1;
  const int rb0 = bch * 32;

  { // stage this wg's W slice (hi+lo) into LDS, frag-linear
    const uint4* sh = (const uint4*)(whi + (size_t)j * 16384);
    const uint4* sl = (const uint4*)(wlo + (size_t)j * 16384);
    uint4* dh = (uint4*)Wh; uint4* dl = (uint4*)Wl;
    for (int i = tid; i < 2048; i += 128){ dh[i] = sh[i]; dl[i] = sl[i]; }
  }
  __syncthreads();

  unsigned int* gflags = flags + g * 64;
  unsigned short* sbg = sbuf + (size_t)g * 2 * 32 * DD;

  const int d   = (j << 4) | (l & 15);              // global feature col
  const int rl0 = (w << 4) | ((l >> 4) << 2);       // local row base (C layout)
  const float inv32 = 0.03125f;

  f32x4 acc = (f32x4){0.f, 0.f, 0.f, 0.f};
  float ev[4];
  {
    int te0 = dir ? (TS - 1) : 0;
    #pragma unroll
    for (int i = 0; i < 4; ++i) ev[i] = load_e<EF32>(e_in, te0, rb0 + rl0 + i, d);
  }

  for (int t = 0; t < TS; ++t){
    float sv[4];
    #pragma unroll
    for (int i = 0; i < 4; ++i) sv[i] = erff(ev[i] + acc[i] * inv32);

    if (t == TS - 1){
      #pragma unroll
      for (int i = 0; i < 4; ++i)
        sfin[(((size_t)(dir * NB + rb0 + rl0 + i)) << 10) | (unsigned)d] = sv[i];
      break;
    }

    unsigned short* sb = sbg + (t & 1) * 32 * DD;   // double buffer
    #pragma unroll
    for (int i = 0; i < 4; ++i) sb[((rl0 + i) << 10) | (unsigned)d] = f32_bf16(sv[i]);

    __syncthreads();                                 // drains both waves' stores
    if (tid == 0){
      __threadfence();                               // device-visible release
      __hip_atomic_store(&gflags[j], (unsigned)(t + 1),
                         __ATOMIC_RELAXED, __HIP_MEMORY_SCOPE_AGENT);
    }

    { // prefetch next e under the poll
      int te2 = dir ? (TS - 2 - t) : (t + 1);
      #pragma unroll
      for (int i = 0; i < 4; ++i) ev[i] = load_e<EF32>(e_in, te2, rb0 + rl0 + i, d);
    }

    const unsigned tgt = (unsigned)(t + 1);          // wait: each lane polls one flag
    while (true){
      unsigned f = __hip_atomic_load(&gflags[l], __ATOMIC_RELAXED, __HIP_MEMORY_SCOPE_AGENT);
      if (__all((int)(f >= tgt))) break;
      __builtin_amdgcn_s_sleep(1);
    }
    __threadfence();                                 // acquire: invalidate stale L1

    // carry' = s @ (Whi + Wlo); 4 independent accumulator chains
    f32x4 a0 = (f32x4){0,0,0,0}, a1 = (f32x4){0,0,0,0};
    f32x4 a2 = (f32x4){0,0,0,0}, a3 = (f32x4){0,0,0,0};
    const unsigned short* srow = sb + (((w << 4) | (l & 15)) << 10) + ((l >> 4) << 3);
    #pragma unroll
    for (int ks = 0; ks < 32; ks += 2){
      bf16x8 aA  = *(const bf16x8*)(srow + ks * 32);
      bf16x8 aB  = *(const bf16x8*)(srow + (ks + 1) * 32);
      bf16x8 bh0 = *(const bf16x8*)&Wh[ks * 512 + l * 8];
      bf16x8 bl0 = *(const bf16x8*)&Wl[ks * 512 + l * 8];
      bf16x8 bh1 = *(const bf16x8*)&Wh[(ks + 1) * 512 + l * 8];
      bf16x8 bl1 = *(const bf16x8*)&Wl[(ks + 1) * 512 + l * 8];
      a0 = __builtin_amdgcn_mfma_f32_16x16x32_bf16(aA, bh0, a0, 0, 0, 0);
      a1 = __builtin_amdgcn_mfma_f32_16x16x32_bf16(aA, bl0, a1, 0, 0, 0);
      a2 = __builtin_amdgcn_mfma_f32_16x16x32_bf16(aB, bh1, a2, 0, 0, 0);
      a3 = __builtin_amdgcn_mfma_f32_16x16x32_bf16(aB, bl1, a3, 0, 0, 0);
    }
    acc = (a0 + a1) + (a2 + a3);
  }
}

// ---- final: out[b] = ([sf, sb] @ v) / 32 ----
__global__ __launch_bounds__(256) void finale(const float* __restrict__ sfin,
                                              const float* __restrict__ v,
                                              float* __restrict__ out){
  const int b = blockIdx.x, tid = threadIdx.x;
  float p = 0.f;
  for (int dd = tid; dd < 2 * DD; dd += 256){
    int dir = dd >> 10, d = dd & 1023;
    p += sfin[(((size_t)(dir * NB + b)) << 10) | (unsigned)d] * v[dd];
  }
  #pragma unroll
  for (int off = 32; off > 0; off >>= 1) p += __shfl_down(p, off, 64);
  __shared__ float red[4];
  if ((tid & 63) == 0) red[tid >> 6] = p;
  __syncthreads();
  if (tid == 0) out[b] = (red[0] + red[1] + red[2] + red[3]) * 0.03125f;
}

extern "C" void kernel_launch(void* const* d_in, const int* in_sizes, int n_in,
                              void* d_out, int out_size, void* d_ws, size_t ws_size,
                              hipStream_t stream){
  const float* inp  = (const float*)d_in[0];
  const float* W    = (const float*)d_in[1];
  const float* U    = (const float*)d_in[2];
  const float* bias = (const float*)d_in[3];
  const float* v    = (const float*)d_in[4];
  float* out = (float*)d_out;

  const size_t e_f32_bytes = (size_t)TS * NB * DD * 4;               // 134 MB
  const size_t rest = 4u * 1024 * 1024 + 512u * 1024 + 512u * 1024 + 4096;
  const int ef32 = (ws_size >= e_f32_bytes + rest) ? 1 : 0;

  char* p = (char*)d_ws;
  void* e_buf = (void*)p;              p += ef32 ? e_f32_bytes : e_f32_bytes / 2;
  unsigned short* whi  = (unsigned short*)p; p += 2u * 1024 * 1024;
  unsigned short* wlo  = (unsigned short*)p; p += 2u * 1024 * 1024;
  unsigned short* sbuf = (unsigned short*)p; p += 512u * 1024;
  float* sfin = (float*)p;             p += 512u * 1024;
  unsigned int* flags = (unsigned int*)p;

  hipMemsetAsync(flags, 0, 4096, stream);
  hipLaunchKernelGGL(wprep, dim3(4096), dim3(256), 0, stream, W, whi, wlo);
  if (ef32) hipLaunchKernelGGL((embed_k<1>), dim3(8192), dim3(256), 0, stream, inp, U, bias, e_buf);
  else      hipLaunchKernelGGL((embed_k<0>), dim3(8192), dim3(256), 0, stream, inp, U, bias, e_buf);
  if (ef32) hipLaunchKernelGGL((recur<1>), dim3(256), dim3(128), 0, stream,
                               (const void*)e_buf, whi, wlo, sbuf, sfin, flags);
  else      hipLaunchKernelGGL((recur<0>), dim3(256), dim3(128), 0, stream,
                               (const void*)e_buf, whi, wlo, sbuf, sfin, flags);
  hipLaunchKernelGGL(finale, dim3(64), dim3(256), 0, stream, sfin, v, out);
}

// Round 3
// 3412.115 us; speedup vs baseline: 3.4884x; 3.4884x over previous
//
#include <hip/hip_runtime.h>
#include <stdint.h>

// BidirectionalRNNClassifier on MI355X.
//   embed = inp @ U / 16 + b              (MFMA bf16 hi/lo, ~fp32 accurate)
//   512 sequential steps x 2 directions:  carry = erf(e_t + carry) @ W / 32
//   out = [s_fwd_last, s_bwd_last] @ v / 32
// Recurrence: 4 groups (dir x batch-half of 32 rows) x 16 wgs. Each wg owns a
// 64-col slice of W (single bf16) in 128 KB LDS. Cross-wg s-exchange goes
// through the device coherence point (MALL) via sc0 sc1 loads/stores — NO
// threadfence / L2 writeback anywhere. Ordering: stores -> __syncthreads
// (vmcnt(0) drain) -> relaxed agent flag store; consumers poll flags then
// read s with sc0 sc1 (cache-bypassing, so no invalidate needed).

#define TS 512
#define NB 64
#define DI 256
#define DD 1024
#define NG 4
#define GW 16

typedef float f32x4 __attribute__((ext_vector_type(4)));
typedef short bf16x8 __attribute__((ext_vector_type(8)));

__device__ __forceinline__ unsigned short f32_bf16(float x){
  unsigned u = __float_as_uint(x);
  u += 0x7FFFu + ((u >> 16) & 1u);          // round-nearest-even
  return (unsigned short)(u >> 16);
}
__device__ __forceinline__ float bf16_f32(unsigned short h){
  return __uint_as_float(((unsigned)h) << 16);
}

// ---- W prep: W[k][n] -> bf16, frag-linear per 64-col slice ----
// slice j (64 cols), sub-tile nt (16 cols), kstep ks, lane, elem e:
//   k = ks*32 + 8*(lane>>4) + e, n = j*64 + nt*16 + (lane&15)
//   index = j*65536 + nt*16384 + ks*512 + lane*8 + e
__global__ __launch_bounds__(256) void wprep(const float* __restrict__ W,
                                             unsigned short* __restrict__ whi){
  int idx = blockIdx.x * 256 + threadIdx.x;   // = k*1024 + n
  int k = idx >> 10, n = idx & 1023;
  unsigned short h = f32_bf16(W[idx]);
  int j  = n >> 6;
  int nt = (n >> 4) & 3;
  int ks = k >> 5;
  int e  = k & 7;
  int lane = (((k >> 3) & 3) << 4) | (n & 15);
  whi[(size_t)j * 65536 + nt * 16384 + ks * 512 + lane * 8 + e] = h;
}

// ---- embed GEMM: e[t][b][d] = sum_i inp[b][t][i]*U[i][d]/16 + bias[d] ----
template<int EF32>
__global__ __launch_bounds__(256, 2) void embed_k(const float* __restrict__ inp,
                                                  const float* __restrict__ U,
                                                  const float* __restrict__ bias,
                                                  void* __restrict__ e_out){
  __shared__ __attribute__((aligned(16))) unsigned short Ah[8192], Al[8192], Bh[8192], Bl[8192];
  const int tid = threadIdx.x;
  const int w = tid >> 6, l = tid & 63;
  const int bx = blockIdx.x;
  const int tc = bx & 15, tr = bx >> 4;
  const int R0 = tr * 64, C0 = tc * 64;

  f32x4 acc[4];
  #pragma unroll
  for (int nt = 0; nt < 4; ++nt) acc[nt] = (f32x4){0.f, 0.f, 0.f, 0.f};

  for (int kc = 0; kc < 2; ++kc){
    if (kc) __syncthreads();
    unsigned int* AhU = (unsigned int*)Ah;
    unsigned int* AlU = (unsigned int*)Al;
    for (int it = 0; it < 8; ++it){
      int fi = it * 256 + tid;
      int r = fi >> 5, k4 = fi & 31;
      float4 a = *(const float4*)&inp[((size_t)(R0 + r)) * DI + kc * 128 + k4 * 4];
      unsigned short hx = f32_bf16(a.x), hy = f32_bf16(a.y), hz = f32_bf16(a.z), hw = f32_bf16(a.w);
      unsigned short lx = f32_bf16(a.x - bf16_f32(hx)), ly = f32_bf16(a.y - bf16_f32(hy));
      unsigned short lz = f32_bf16(a.z - bf16_f32(hz)), lw = f32_bf16(a.w - bf16_f32(hw));
      int o = (r * 64 + k4 * 2) ^ ((r & 7) << 2);
      AhU[o]     = (unsigned)hx | ((unsigned)hy << 16);
      AhU[o + 1] = (unsigned)hz | ((unsigned)hw << 16);
      AlU[o]     = (unsigned)lx | ((unsigned)ly << 16);
      AlU[o + 1] = (unsigned)lz | ((unsigned)lw << 16);
    }
    for (int it = 0; it < 8; ++it){
      int fi = it * 256 + tid;
      int kk = fi >> 4, c4 = fi & 15;
      float4 u4 = *(const float4*)&U[((size_t)(kc * 128 + kk)) * DD + C0 + c4 * 4];
      float vals[4] = {u4.x, u4.y, u4.z, u4.w};
      #pragma unroll
      for (int q = 0; q < 4; ++q){
        int c = c4 * 4 + q;
        unsigned short h  = f32_bf16(vals[q]);
        unsigned short lo = f32_bf16(vals[q] - bf16_f32(h));
        int o = (c * 128 + kk) ^ ((c & 7) << 3);
        Bh[o] = h; Bl[o] = lo;
      }
    }
    __syncthreads();
    const int arow = (w << 4) | (l & 15);
    const int koff = (l >> 4) << 3;
    #pragma unroll
    for (int ks = 0; ks < 4; ++ks){
      int ao = (arow * 128 + ks * 32 + koff) ^ ((arow & 7) << 3);
      bf16x8 ah = *(const bf16x8*)&Ah[ao];
      bf16x8 al = *(const bf16x8*)&Al[ao];
      #pragma unroll
      for (int nt = 0; nt < 4; ++nt){
        int brow = (nt << 4) | (l & 15);
        int bo = (brow * 128 + ks * 32 + koff) ^ ((brow & 7) << 3);
        bf16x8 bh = *(const bf16x8*)&Bh[bo];
        bf16x8 bl = *(const bf16x8*)&Bl[bo];
        acc[nt] = __builtin_amdgcn_mfma_f32_16x16x32_bf16(ah, bh, acc[nt], 0, 0, 0);
        acc[nt] = __builtin_amdgcn_mfma_f32_16x16x32_bf16(ah, bl, acc[nt], 0, 0, 0);
        acc[nt] = __builtin_amdgcn_mfma_f32_16x16x32_bf16(al, bh, acc[nt], 0, 0, 0);
      }
    }
  }
  #pragma unroll
  for (int nt = 0; nt < 4; ++nt){
    int d = C0 + (nt << 4) + (l & 15);
    float bv = bias[d];
    #pragma unroll
    for (int i = 0; i < 4; ++i){
      int R = R0 + (w << 4) + ((l >> 4) << 2) + i;
      int b = R >> 9, t = R & 511;
      float val = acc[nt][i] * 0.0625f + bv;
      size_t eo = (((size_t)(t * NB + b)) << 10) | (unsigned)d;
      if (EF32) ((float*)e_out)[eo] = val;
      else      ((unsigned short*)e_out)[eo] = f32_bf16(val);
    }
  }
}

template<int EF32>
__device__ __forceinline__ float load_e(const void* e, int te, int b, int d){
  size_t o = (((size_t)(te * NB + b)) << 10) | (unsigned)d;
  if (EF32) return ((const float*)e)[o];
  return bf16_f32(((const unsigned short*)e)[o]);
}

// ---- recurrence: 64 wgs x 128 threads; 4 groups x 16 wgs ----
template<int EF32>
__global__ __launch_bounds__(128, 1) void recur(const void* __restrict__ e_in,
                                                const unsigned short* __restrict__ whi,
                                                unsigned short* __restrict__ sbuf,
                                                float* __restrict__ sfin,
                                                unsigned int* __restrict__ flags){
  __shared__ __attribute__((aligned(16))) unsigned short Wh[65536];   // 128 KB
  const int tid = threadIdx.x;
  const int w = tid >> 6, l = tid & 63;
  const int bid = blockIdx.x;
  const int g = bid >> 4;           // group = dir*2 + batch-chunk
  const int j = bid & 15;           // 64-col N-slice
  const int dir = g >> 1, rb0 = (g & 1) * 32;

  { // stage this wg's W slice into LDS (frag-linear, once)
    const uint4* src = (const uint4*)(whi + (size_t)j * 65536);
    uint4* dst = (uint4*)Wh;
    for (int i = tid; i < 8192; i += 128) dst[i] = src[i];
  }
  __syncthreads();

  unsigned int* gflags = flags + g * GW;
  unsigned short* sbg = sbuf + (size_t)g * 2 * 32 * DD;

  const int d0 = j * 64;
  const int colq = l & 15;
  const int rl = (w << 4) + ((l >> 4) << 2);   // this thread's 4-row base (C layout)
  const float inv32 = 0.03125f;

  f32x4 acc[4];
  #pragma unroll
  for (int nt = 0; nt < 4; ++nt) acc[nt] = (f32x4){0.f, 0.f, 0.f, 0.f};

  float ev[4][4];
  {
    int te0 = dir ? (TS - 1) : 0;
    #pragma unroll
    for (int nt = 0; nt < 4; ++nt)
      #pragma unroll
      for (int i = 0; i < 4; ++i)
        ev[nt][i] = load_e<EF32>(e_in, te0, rb0 + rl + i, d0 + nt * 16 + colq);
  }

  for (int t = 0; t < TS; ++t){
    float sv[4][4];
    #pragma unroll
    for (int nt = 0; nt < 4; ++nt)
      #pragma unroll
      for (int i = 0; i < 4; ++i)
        sv[nt][i] = erff(ev[nt][i] + acc[nt][i] * inv32);

    if (t == TS - 1){
      #pragma unroll
      for (int nt = 0; nt < 4; ++nt)
        #pragma unroll
        for (int i = 0; i < 4; ++i)
          sfin[(((size_t)(dir * NB + rb0 + rl + i)) << 10) | (unsigned)(d0 + nt * 16 + colq)] = sv[nt][i];
      break;
    }

    unsigned short* sb = sbg + (t & 1) * 32768;   // double buffer
    #pragma unroll
    for (int nt = 0; nt < 4; ++nt)
      #pragma unroll
      for (int i = 0; i < 4; ++i){
        unsigned short* p = sb + (((unsigned)(rl + i)) << 10) + (unsigned)(d0 + nt * 16 + colq);
        unsigned val = f32_bf16(sv[nt][i]);
        asm volatile("global_store_short %0, %1, off sc0 sc1" :: "v"(p), "v"(val) : "memory");
      }

    __syncthreads();                               // per-wave vmcnt(0) drain + join
    if (tid == 0)
      __hip_atomic_store(&gflags[j], (unsigned)(t + 1),
                         __ATOMIC_RELAXED, __HIP_MEMORY_SCOPE_AGENT);

    { // prefetch next e under the poll (plain cached loads)
      int te2 = dir ? (TS - 2 - t) : (t + 1);
      #pragma unroll
      for (int nt = 0; nt < 4; ++nt)
        #pragma unroll
        for (int i = 0; i < 4; ++i)
          ev[nt][i] = load_e<EF32>(e_in, te2, rb0 + rl + i, d0 + nt * 16 + colq);
    }

    const unsigned tgt = (unsigned)(t + 1);
    unsigned f;
    do {
      f = __hip_atomic_load(&gflags[l & 15], __ATOMIC_RELAXED, __HIP_MEMORY_SCOPE_AGENT);
    } while (!__all((int)(f >= tgt)));
    asm volatile("" ::: "memory");

    // carry' = s @ W : wave w owns rows 16w..16w+15; 4 n-tile acc chains.
    const unsigned short* srow = sb + (((unsigned)((w << 4) + (l & 15))) << 10) + ((l >> 4) << 3);
    f32x4 c0 = (f32x4){0,0,0,0}, c1 = (f32x4){0,0,0,0};
    f32x4 c2 = (f32x4){0,0,0,0}, c3 = (f32x4){0,0,0,0};
    bf16x8 af[2][8];
    #pragma unroll
    for (int ki = 0; ki < 8; ++ki){
      const unsigned short* p = srow + ki * 32;
      asm volatile("global_load_dwordx4 %0, %1, off sc0 sc1" : "=v"(af[0][ki]) : "v"(p));
    }
    const bf16x8* wp = (const bf16x8*)Wh;
    #pragma unroll
    for (int kc = 0; kc < 4; ++kc){
      if (kc < 3){
        #pragma unroll
        for (int ki = 0; ki < 8; ++ki){
          const unsigned short* p = srow + (kc + 1) * 256 + ki * 32;
          asm volatile("global_load_dwordx4 %0, %1, off sc0 sc1" : "=v"(af[(kc + 1) & 1][ki]) : "v"(p));
        }
        asm volatile("s_waitcnt vmcnt(8)" ::: "memory");
      } else {
        asm volatile("s_waitcnt vmcnt(0)" ::: "memory");
      }
      __builtin_amdgcn_sched_barrier(0);
      #pragma unroll
      for (int ki = 0; ki < 8; ++ki){
        int ks = kc * 8 + ki;
        bf16x8 a = af[kc & 1][ki];
        c0 = __builtin_amdgcn_mfma_f32_16x16x32_bf16(a, wp[          ks * 64 + l], c0, 0, 0, 0);
        c1 = __builtin_amdgcn_mfma_f32_16x16x32_bf16(a, wp[2048 +    ks * 64 + l], c1, 0, 0, 0);
        c2 = __builtin_amdgcn_mfma_f32_16x16x32_bf16(a, wp[4096 +    ks * 64 + l], c2, 0, 0, 0);
        c3 = __builtin_amdgcn_mfma_f32_16x16x32_bf16(a, wp[6144 +    ks * 64 + l], c3, 0, 0, 0);
      }
    }
    acc[0] = c0; acc[1] = c1; acc[2] = c2; acc[3] = c3;
  }
}

// ---- final: out[b] = ([sf, sb] @ v) / 32 ----
__global__ __launch_bounds__(256) void finale(const float* __restrict__ sfin,
                                              const float* __restrict__ v,
                                              float* __restrict__ out){
  const int b = blockIdx.x, tid = threadIdx.x;
  float p = 0.f;
  for (int dd = tid; dd < 2 * DD; dd += 256){
    int dir = dd >> 10, d = dd & 1023;
    p += sfin[(((size_t)(dir * NB + b)) << 10) | (unsigned)d] * v[dd];
  }
  #pragma unroll
  for (int off = 32; off > 0; off >>= 1) p += __shfl_down(p, off, 64);
  __shared__ float red[4];
  if ((tid & 63) == 0) red[tid >> 6] = p;
  __syncthreads();
  if (tid == 0) out[b] = (red[0] + red[1] + red[2] + red[3]) * 0.03125f;
}

extern "C" void kernel_launch(void* const* d_in, const int* in_sizes, int n_in,
                              void* d_out, int out_size, void* d_ws, size_t ws_size,
                              hipStream_t stream){
  const float* inp  = (const float*)d_in[0];
  const float* W    = (const float*)d_in[1];
  const float* U    = (const float*)d_in[2];
  const float* bias = (const float*)d_in[3];
  const float* v    = (const float*)d_in[4];
  float* out = (float*)d_out;

  const size_t e_f32_bytes = (size_t)TS * NB * DD * 4;               // 134 MB
  const size_t rest = 2u * 1024 * 1024 + 512u * 1024 + 512u * 1024 + 4096;
  const int ef32 = (ws_size >= e_f32_bytes + rest) ? 1 : 0;

  char* p = (char*)d_ws;
  void* e_buf = (void*)p;              p += ef32 ? e_f32_bytes : e_f32_bytes / 2;
  unsigned short* whi  = (unsigned short*)p; p += 2u * 1024 * 1024;
  unsigned short* sbuf = (unsigned short*)p; p += 512u * 1024;
  float* sfin = (float*)p;             p += 512u * 1024;
  unsigned int* flags = (unsigned int*)p;

  hipMemsetAsync(flags, 0, 4096, stream);
  hipLaunchKernelGGL(wprep, dim3(4096), dim3(256), 0, stream, W, whi);
  if (ef32) hipLaunchKernelGGL((embed_k<1>), dim3(8192), dim3(256), 0, stream, inp, U, bias, e_buf);
  else      hipLaunchKernelGGL((embed_k<0>), dim3(8192), dim3(256), 0, stream, inp, U, bias, e_buf);
  if (ef32) hipLaunchKernelGGL((recur<1>), dim3(64), dim3(128), 0, stream,
                               (const void*)e_buf, whi, sbuf, sfin, flags);
  else      hipLaunchKernelGGL((recur<0>), dim3(64), dim3(128), 0, stream,
                               (const void*)e_buf, whi, sbuf, sfin, flags);
  hipLaunchKernelGGL(finale, dim3(64), dim3(256), 0, stream, sfin, v, out);
}